// Round 18
// baseline (306.977 us; speedup 1.0000x reference)
//
#include <hip/hip_runtime.h>
#include <hip/hip_fp16.h>

#define U_N 50000
#define I_N 100000
#define E_N 1600000
#define B_N 16384
#define UI_N (U_N + I_N)   // 150000
#define NB_U 782           // ceil(50000/64)
#define NB_I 1563          // ceil(100000/64)
#define NBK 586            // ceil(150000/256) buckets, 256 nodes each
#define CAP 10240          // entries per bucket (mean 8192 max, ~22 sigma margin)
#define NBLD 512           // blocks in k_build1
#define CHUNK (E_N / NBLD) // 3125 edges per block
#define COL_CAP 3300000    // >= 2E exact CSR slots
#define MAXACT 32768       // max unique dot nodes (16384 users + 16384 items)

// ------- CSR build phase 1 (block-local binning) + fused active-node flag/compact ----
__global__ __launch_bounds__(1024) void k_build1(
    const int* __restrict__ eu, const int* __restrict__ ei,
    int* __restrict__ bcnt, int* __restrict__ storage,
    const int* __restrict__ uIdx, const int* __restrict__ iIdx,
    int* __restrict__ flag, int* __restrict__ list, int* __restrict__ nm) {
  __shared__ int hist[NBK];
  __shared__ int lbase[NBK];
  __shared__ int loff[NBK];
  int t = threadIdx.x;
  // fused flag/compact duty: blocks 0..15 cover B_N pair indices
  if (blockIdx.x < (B_N + 1023) / 1024) {
    int b = blockIdx.x * 1024 + t;
    if (b < B_N) {
      int u = uIdx[b];
      if (atomicExch(&flag[u], 1) == 0) list[atomicAdd(nm, 1)] = u;
      int it = U_N + iIdx[b];
      if (atomicExch(&flag[it], 1) == 0) list[atomicAdd(nm, 1)] = it;
    }
  }
  for (int b = t; b < NBK; b += 1024) { hist[b] = 0; loff[b] = 0; }
  __syncthreads();
  int e0 = blockIdx.x * CHUNK;
  int myu[4], myi[4];
  int ne = 0;
#pragma unroll
  for (int k = 0; k < 4; k++) {
    int e = e0 + t + 1024 * k;
    if (e < e0 + CHUNK) {
      int u = eu[e], it = ei[e];
      myu[k] = u;
      myi[k] = it;
      ne = k + 1;
      atomicAdd(&hist[u >> 8], 1);
      atomicAdd(&hist[(U_N + it) >> 8], 1);
    }
  }
  __syncthreads();
  for (int b = t; b < NBK; b += 1024) {
    int h = hist[b];
    lbase[b] = h ? atomicAdd(&bcnt[b], h) : 0;
  }
  __syncthreads();
#pragma unroll
  for (int k = 0; k < 4; k++) {
    if (k < ne) {
      int u = myu[k], it = myi[k];
      int k2 = U_N + it;
      int b1 = u >> 8;
      int s1 = lbase[b1] + atomicAdd(&loff[b1], 1);
      storage[(size_t)b1 * CAP + s1] = ((u & 255) << 17) | it;
      int b2 = k2 >> 8;
      int s2 = lbase[b2] + atomicAdd(&loff[b2], 1);
      storage[(size_t)b2 * CAP + s2] = ((k2 & 255) << 17) | u;
    }
  }
}

// ---- CSR build phase 2: count pass -> LDS prefix -> atomic base alloc -> scatter ----
// Bucket bases allocated via global cursor (arbitrary order); per-node extent is
// published as {ptr[n], pend[n]} since bucket regions are no longer adjacent.
__global__ __launch_bounds__(256) void k_build2(const int* __restrict__ bcnt,
                                                const int* __restrict__ storage,
                                                int* __restrict__ gcur,
                                                int* __restrict__ ptr,
                                                int* __restrict__ pend,
                                                int* __restrict__ col) {
  __shared__ int c[256];
  __shared__ int sc[256];
  __shared__ int pb[256];
  __shared__ int cur[256];
  __shared__ int baseS;
  int b = blockIdx.x;
  int t = threadIdx.x;
  c[t] = 0;
  __syncthreads();
  int n = bcnt[b];
  const int* s = storage + (size_t)b * CAP;
  for (int i = t; i < n; i += 256) atomicAdd(&c[s[i] >> 17], 1);
  __syncthreads();
  int deg = c[t];
  sc[t] = deg;
  __syncthreads();
  int val = deg;
  for (int off = 1; off < 256; off <<= 1) {
    int x = (t >= off) ? sc[t - off] : 0;
    __syncthreads();
    val += x;
    sc[t] = val;
    __syncthreads();
  }
  if (t == 255) baseS = atomicAdd(gcur, val);  // val == bucket total at t=255
  __syncthreads();
  int base = baseS;
  int myPtr = base + (val - deg);
  pb[t] = myPtr;
  cur[t] = 0;
  int node = b * 256 + t;
  if (node < UI_N) {
    ptr[node] = myPtr;
    pend[node] = myPtr + deg;
  }
  __syncthreads();
  for (int i = t; i < n; i += 256) {
    int e = s[i];
    int local = e >> 17;
    int slot = pb[local] + atomicAdd(&cur[local], 1);
    col[slot] = e & 0x1FFFF;
  }
}

// ---------------- Fused matmul + attention scores (users + items, one launch) ---------
__global__ __launch_bounds__(256) void k_mm2(
    const float* __restrict__ Xu32, const float* __restrict__ Xi32,
    const __half* __restrict__ Xu16, const __half* __restrict__ Xi16,
    const float* __restrict__ Wu, const float* __restrict__ Wi,
    const float* __restrict__ a, int layer,
    __half* __restrict__ fA_U, __half* __restrict__ fA_I,
    __half* __restrict__ s16U, __half* __restrict__ s16I) {
  __shared__ float Wl[4096];
  __shared__ float Xs[4096];
  const bool isU = blockIdx.x < NB_U;
  const int N = isU ? U_N : I_N;
  const int base = (isU ? blockIdx.x : blockIdx.x - NB_U) * 64;
  const float* W = isU ? Wu : Wi;
  __half* f16 = isU ? fA_U : fA_I;
  __half* s16 = isU ? s16U : s16I;
  const int aoff = (layer == 1) ? (isU ? 0 : 8) : (isU ? 0 : 64);
  int t = threadIdx.x;

  if (layer == 1) {
#pragma unroll
    for (int k = 0; k < 4; k++) {
      int i = t + 256 * k;
      int h = i >> 7, d = (i >> 1) & 63, half = i & 1;
      float4 v = *(const float4*)(W + h * 512 + d * 8 + half * 4);
      *(float4*)(Wl + d * 64 + h * 8 + half * 4) = v;
    }
    const float* X = isU ? Xu32 : Xi32;
#pragma unroll
    for (int k = 0; k < 4; k++) {
      int i = t + 256 * k;
      int r = i >> 4, ch = i & 15;
      int node = base + r;
      float4 v = make_float4(0.f, 0.f, 0.f, 0.f);
      if (node < N) v = *(const float4*)(X + (size_t)node * 64 + ch * 4);
      *(float4*)(Xs + r * 64 + ch * 4) = v;
    }
  } else {
#pragma unroll
    for (int k = 0; k < 4; k++) {
      int i = t + 256 * k;
      *(float4*)(Wl + i * 4) = *(const float4*)(W + i * 4);
    }
    const __half* X = isU ? Xu16 : Xi16;
#pragma unroll
    for (int k = 0; k < 4; k++) {
      int i = t + 256 * k;
      int r = i >> 4, ch = i & 15;
      int node = base + r;
      float4 v = make_float4(0.f, 0.f, 0.f, 0.f);
      if (node < N) {
        const __half2* hp = (const __half2*)(X + (size_t)node * 64 + ch * 4);
        float2 f0 = __half22float2(hp[0]);
        float2 f1 = __half22float2(hp[1]);
        v = make_float4(f0.x, f0.y, f1.x, f1.y);
      }
      *(float4*)(Xs + r * 64 + ch * 4) = v;
    }
  }
  __syncthreads();

  const int c0 = t & 31;
  const int rb = t >> 5;
  float acc0[8], acc1[8];
#pragma unroll
  for (int k = 0; k < 8; k++) { acc0[k] = 0.f; acc1[k] = 0.f; }

  for (int d0 = 0; d0 < 64; d0 += 4) {
    float2 wA = *(float2*)(Wl + (d0 + 0) * 64 + 2 * c0);
    float2 wB = *(float2*)(Wl + (d0 + 1) * 64 + 2 * c0);
    float2 wC = *(float2*)(Wl + (d0 + 2) * 64 + 2 * c0);
    float2 wD = *(float2*)(Wl + (d0 + 3) * 64 + 2 * c0);
#pragma unroll
    for (int k = 0; k < 8; k++) {
      float4 x = *(float4*)(Xs + (rb + 8 * k) * 64 + d0);
      acc0[k] += x.x * wA.x + x.y * wB.x + x.z * wC.x + x.w * wD.x;
      acc1[k] += x.x * wA.y + x.y * wB.y + x.z * wC.y + x.w * wD.y;
    }
  }

  float av0, av1;
  if (layer == 1) {
    int h = c0 >> 2, j = 2 * (c0 & 3);
    av0 = a[h * 16 + aoff + j];
    av1 = a[h * 16 + aoff + j + 1];
  } else {
    av0 = a[aoff + 2 * c0];
    av1 = a[aoff + 2 * c0 + 1];
  }
#pragma unroll
  for (int k = 0; k < 8; k++) {
    int node = base + rb + 8 * k;
    float s = acc0[k] * av0 + acc1[k] * av1;
    s += __shfl_xor(s, 1);
    s += __shfl_xor(s, 2);
    if (layer != 1) {
      s += __shfl_xor(s, 4);
      s += __shfl_xor(s, 8);
      s += __shfl_xor(s, 16);
    }
    if (node < N) {
      float2 f;
      f.x = acc0[k];
      f.y = acc1[k];
      *(__half2*)(f16 + (size_t)node * 64 + 2 * c0) = __float22half2_rn(f);
      if (layer == 1) {
        if ((c0 & 3) == 0) s16[node * 8 + (c0 >> 2)] = __float2half_rn(s);
      } else {
        if (c0 == 0) s16[node] = __float2half_rn(s);
      }
    }
  }
}

// ---------------- Fused aggregation body: TWO nodes per wave, unroll-4 ----------------
// Inactive half-waves: deg forced to 0 — runaway-proof. Row extent = {ptr, pend}.
template <int LAYER>
__device__ __forceinline__ void agg_body(
    const int* __restrict__ ptr, const int* __restrict__ pend,
    const int* __restrict__ col,
    const __half* __restrict__ fA_U, const __half* __restrict__ fA_I,
    __half* __restrict__ fB_U, __half* __restrict__ fB_I,
    const __half* __restrict__ s16U, const __half* __restrict__ s16I,
    const int* __restrict__ list, const int* __restrict__ nm) {
  int gid = blockIdx.x * blockDim.x + threadIdx.x;
  int wv = gid >> 6;
  int l = threadIdx.x & 63;
  int half = l >> 5;
  int idx = wv * 2 + half;
  bool act = true;
  int n;
  if (LAYER == 2) {
    act = idx < *nm;
    n = act ? list[idx] : 0;
  } else {
    n = idx;                         // UI_N even; pairs never straddle U/I
  }
  int lh = l & 31;
  int g = lh >> 3;
  int cc = lh & 7;
  bool isU = n < U_N;
  int nl = isU ? n : n - U_N;
  const char* nbrF = (const char*)(isU ? fA_I : fA_U);
  const char* nbrS = (const char*)(isU ? s16I : s16U);
  const __half* selfS = isU ? s16U : s16I;
  const __half* selfF = isU ? fA_U : fA_I;
  __half* outp = isU ? fB_U : fB_I;
  const char* colc = (const char*)col;

  int beg = ptr[n], endA = pend[n];
  int deg = act ? (endA - beg) : 0;  // hazard clamp: inactive -> no loop
  unsigned coff = ((unsigned)(beg + g)) << 2;
  const unsigned begb = (unsigned)beg << 2;
  const unsigned fsh = (unsigned)cc << 4;
  const unsigned ssh = (LAYER == 1) ? ((unsigned)cc << 1) : 0u;
  float sself = (LAYER == 1) ? __half2float(selfS[(size_t)nl * 8 + cc])
                             : __half2float(selfS[nl]);
  float acc[8];
#pragma unroll
  for (int k = 0; k < 8; k++) acc[k] = 0.f;
  float wsum = 0.f;

  auto edge = [&](unsigned off) {
    int nb = *(const int*)(colc + off);
    unsigned so = (LAYER == 1) ? (((unsigned)nb << 4) + ssh) : ((unsigned)nb << 1);
    float x = sself + __half2float(*(const __half*)(nbrS + so));
    float4 r = *(const float4*)(nbrF + (((unsigned)nb << 7) + fsh));
    float w = __expf(-fmaxf(x, 0.2f * x));
    wsum += w;
    const __half* h = (const __half*)&r;
#pragma unroll
    for (int k = 0; k < 8; k++) acc[k] += w * (float)h[k];
  };
  auto edgem = [&](unsigned off, bool valid) {
    unsigned o = valid ? off : begb;
    int nb = *(const int*)(colc + o);
    unsigned so = (LAYER == 1) ? (((unsigned)nb << 4) + ssh) : ((unsigned)nb << 1);
    float x = sself + __half2float(*(const __half*)(nbrS + so));
    float4 r = *(const float4*)(nbrF + (((unsigned)nb << 7) + fsh));
    float w = valid ? __expf(-fmaxf(x, 0.2f * x)) : 0.f;
    wsum += w;
    const __half* h = (const __half*)&r;
#pragma unroll
    for (int k = 0; k < 8; k++) acc[k] += w * (float)h[k];
  };

  int q = deg >> 4;
  for (; q > 0; q--) {
    edge(coff);
    edge(coff + 16);
    edge(coff + 32);
    edge(coff + 48);
    coff += 64;
  }
  int rem = deg & 15;
  if (rem) {
    edgem(coff, g < rem);
    edgem(coff + 16, (4 + g) < rem);
    edgem(coff + 32, (8 + g) < rem);
    edgem(coff + 48, (12 + g) < rem);
  }

#pragma unroll
  for (int k = 0; k < 8; k++) {
    acc[k] += __shfl_xor(acc[k], 8);
    acc[k] += __shfl_xor(acc[k], 16);
  }
  wsum += __shfl_xor(wsum, 8);
  wsum += __shfl_xor(wsum, 16);

  if (lh < 8 && act) {
    float4 raw = *(const float4*)(selfF + (size_t)nl * 64 + cc * 8);
    const __half2* sp = (const __half2*)&raw;
    float2 s0 = __half22float2(sp[0]);
    float2 s1 = __half22float2(sp[1]);
    float2 s2 = __half22float2(sp[2]);
    float2 s3 = __half22float2(sp[3]);
    float v[8] = {s0.x, s0.y, s1.x, s1.y, s2.x, s2.y, s3.x, s3.y};
    if (deg > 0) {
      float inv = 1.f / wsum;
#pragma unroll
      for (int k = 0; k < 8; k++) v[k] += acc[k] * inv;
    }
#pragma unroll
    for (int k = 0; k < 8; k++) v[k] = (v[k] > 0.f) ? v[k] : (__expf(v[k]) - 1.f);
    __half2 o[4];
    o[0] = __floats2half2_rn(v[0], v[1]);
    o[1] = __floats2half2_rn(v[2], v[3]);
    o[2] = __floats2half2_rn(v[4], v[5]);
    o[3] = __floats2half2_rn(v[6], v[7]);
    *(float4*)(outp + (size_t)nl * 64 + cc * 8) = *(float4*)o;
  }
}

__global__ __launch_bounds__(256) void k_aggL1(
    const int* __restrict__ ptr, const int* __restrict__ pend,
    const int* __restrict__ col,
    const __half* __restrict__ fA_U, const __half* __restrict__ fA_I,
    __half* __restrict__ fB_U, __half* __restrict__ fB_I,
    const __half* __restrict__ s16U, const __half* __restrict__ s16I) {
  agg_body<1>(ptr, pend, col, fA_U, fA_I, fB_U, fB_I, s16U, s16I, nullptr, nullptr);
}

__global__ __launch_bounds__(256) void k_aggL2(
    const int* __restrict__ ptr, const int* __restrict__ pend,
    const int* __restrict__ col,
    const __half* __restrict__ fA_U, const __half* __restrict__ fA_I,
    __half* __restrict__ fB_U, __half* __restrict__ fB_I,
    const __half* __restrict__ s2U, const __half* __restrict__ s2I,
    const int* __restrict__ list, const int* __restrict__ nm) {
  agg_body<2>(ptr, pend, col, fA_U, fA_I, fB_U, fB_I, s2U, s2I, list, nm);
}

// ---------------- Final pair dot (fp16 inputs; 32 pairs/block, 8 lanes each) ----------
__global__ void k_dot(const int* __restrict__ uIdx, const int* __restrict__ iIdx,
                      const __half* __restrict__ u_f, const __half* __restrict__ i_f,
                      float* __restrict__ out) {
  int t = threadIdx.x;
  int pair = blockIdx.x * 32 + (t >> 3);
  int cc = t & 7;
  float4 ra = *(const float4*)(u_f + (size_t)uIdx[pair] * 64 + cc * 8);
  float4 rb = *(const float4*)(i_f + (size_t)iIdx[pair] * 64 + cc * 8);
  const __half* ha = (const __half*)&ra;
  const __half* hb = (const __half*)&rb;
  float v = 0.f;
#pragma unroll
  for (int k = 0; k < 8; k++) v += (float)ha[k] * (float)hb[k];
  v += __shfl_xor(v, 1);
  v += __shfl_xor(v, 2);
  v += __shfl_xor(v, 4);
  if (cc == 0) out[pair] = v;
}

extern "C" void kernel_launch(void* const* d_in, const int* in_sizes, int n_in,
                              void* d_out, int out_size, void* d_ws, size_t ws_size,
                              hipStream_t stream) {
  const int* userIdx = (const int*)d_in[0];
  const int* itemIdx = (const int*)d_in[1];
  const int* edge_u = (const int*)d_in[2];
  const int* edge_i = (const int*)d_in[3];
  const float* uEmbd = (const float*)d_in[4];
  const float* iEmbd = (const float*)d_in[5];
  const float* Wu_h = (const float*)d_in[6];
  const float* Wi_h = (const float*)d_in[7];
  const float* a_h = (const float*)d_in[8];
  const float* Wu_out = (const float*)d_in[9];
  const float* Wi_out = (const float*)d_in[10];
  const float* a_out = (const float*)d_in[11];
  float* out = (float*)d_out;

  char* w = (char*)d_ws;
  size_t off = 0;
  auto alloc = [&](size_t bytes) -> void* {
    void* p = w + off;
    off += (bytes + 511) & ~(size_t)511;
    return p;
  };
  // zero-init block: bcnt[NBK] | nm | gcur | pad | flag[UI_N] — one memset
  int* bcnt = (int*)alloc((size_t)(NBK + 16 + UI_N) * 4);
  int* nm = bcnt + NBK;
  int* gcur = bcnt + NBK + 1;
  int* flag = bcnt + NBK + 16;
  int* ptr = (int*)alloc((size_t)UI_N * 4);
  int* pend = (int*)alloc((size_t)UI_N * 4);
  int* list = (int*)alloc((size_t)MAXACT * 4);
  int* col = (int*)alloc((size_t)COL_CAP * 4);
  // fA (pre-agg gather tables) and scores: NOT aliased with storage
  __half* fA_U = (__half*)alloc((size_t)U_N * 64 * 2);
  __half* fA_I = (__half*)alloc((size_t)I_N * 64 * 2);
  __half* s16U = (__half*)alloc((size_t)U_N * 8 * 2);
  __half* s16I = (__half*)alloc((size_t)I_N * 8 * 2);
  __half* s2U = (__half*)alloc((size_t)U_N * 2);
  __half* s2I = (__half*)alloc((size_t)I_N * 2);
  // union tail: storage (24 MB, dead after k_build2) aliases fB (first write: agg L1)
  size_t union_off = off;
  int* storage = (int*)alloc((size_t)NBK * CAP * 4);
  size_t end_storage = off;
  off = union_off;
  __half* fB_U = (__half*)alloc((size_t)U_N * 64 * 2);
  __half* fB_I = (__half*)alloc((size_t)I_N * 64 * 2);
  if (off < end_storage) off = end_storage;

  // CSR/CSC build (count+ptr fused in build2; flag/compact fused in build1)
  hipMemsetAsync(bcnt, 0, (size_t)(NBK + 16 + UI_N) * 4, stream);
  k_build1<<<NBLD, 1024, 0, stream>>>(edge_u, edge_i, bcnt, storage,
                                      userIdx, itemIdx, flag, list, nm);
  k_build2<<<NBK, 256, 0, stream>>>(bcnt, storage, gcur, ptr, pend, col);

  // Layer 1: mm (fp32 in -> fA fp16 + scores); agg over ALL nodes (fA -> fB)
  k_mm2<<<NB_U + NB_I, 256, 0, stream>>>(uEmbd, iEmbd, (const __half*)nullptr,
                                         (const __half*)nullptr, Wu_h, Wi_h, a_h, 1,
                                         fA_U, fA_I, s16U, s16I);
  k_aggL1<<<UI_N * 32 / 256, 256, 0, stream>>>(ptr, pend, col, fA_U, fA_I,
                                               fB_U, fB_I, s16U, s16I);

  // Layer 2: mm over ALL nodes (fB -> fA + s2); agg over ACTIVE nodes only
  k_mm2<<<NB_U + NB_I, 256, 0, stream>>>((const float*)nullptr, (const float*)nullptr,
                                         fB_U, fB_I, Wu_out, Wi_out, a_out, 2,
                                         fA_U, fA_I, s2U, s2I);
  k_aggL2<<<MAXACT * 32 / 256, 256, 0, stream>>>(ptr, pend, col, fA_U, fA_I,
                                                 fB_U, fB_I, s2U, s2I, list, nm);

  // Final per-pair dot (fp16 features)
  k_dot<<<B_N / 32, 256, 0, stream>>>(userIdx, itemIdx, fB_U, fB_I, out);
}

// Round 19
// 306.676 us; speedup vs baseline: 1.0010x; 1.0010x over previous
//
#include <hip/hip_runtime.h>
#include <hip/hip_fp16.h>

#define U_N 50000
#define I_N 100000
#define E_N 1600000
#define B_N 16384
#define UI_N (U_N + I_N)   // 150000
#define NB_U 782           // ceil(50000/64)
#define NB_I 1563          // ceil(100000/64)
#define NBK 586            // ceil(150000/256) buckets, 256 nodes each
#define CAP 10240          // entries per bucket (mean 8192 max, ~22 sigma margin)
#define NBLD 512           // blocks in k_build1
#define CHUNK (E_N / NBLD) // 3125 edges per block
#define COL_CAP 3300000    // >= 2E exact CSR slots
#define MAXACT 32768       // max unique dot nodes (16384 users + 16384 items)

// ---------------- CSR build: phase 1 (block-local binning, packed 4B entries) ---------
__global__ __launch_bounds__(1024) void k_build1(
    const int* __restrict__ eu, const int* __restrict__ ei,
    int* __restrict__ bcnt, int* __restrict__ storage) {
  __shared__ int hist[NBK];
  __shared__ int lbase[NBK];
  __shared__ int loff[NBK];
  int t = threadIdx.x;
  for (int b = t; b < NBK; b += 1024) { hist[b] = 0; loff[b] = 0; }
  __syncthreads();
  int e0 = blockIdx.x * CHUNK;
  int myu[4], myi[4];
  int ne = 0;
#pragma unroll
  for (int k = 0; k < 4; k++) {
    int e = e0 + t + 1024 * k;
    if (e < e0 + CHUNK) {
      int u = eu[e], it = ei[e];
      myu[k] = u;
      myi[k] = it;
      ne = k + 1;
      atomicAdd(&hist[u >> 8], 1);
      atomicAdd(&hist[(U_N + it) >> 8], 1);
    }
  }
  __syncthreads();
  for (int b = t; b < NBK; b += 1024) {
    int h = hist[b];
    lbase[b] = h ? atomicAdd(&bcnt[b], h) : 0;
  }
  __syncthreads();
#pragma unroll
  for (int k = 0; k < 4; k++) {
    if (k < ne) {
      int u = myu[k], it = myi[k];
      int k2 = U_N + it;
      int b1 = u >> 8;
      int s1 = lbase[b1] + atomicAdd(&loff[b1], 1);
      storage[(size_t)b1 * CAP + s1] = ((u & 255) << 17) | it;
      int b2 = k2 >> 8;
      int s2 = lbase[b2] + atomicAdd(&loff[b2], 1);
      storage[(size_t)b2 * CAP + s2] = ((k2 & 255) << 17) | u;
    }
  }
}

// ---------------- single-block exclusive scan over bucket entry counts ----------------
__global__ __launch_bounds__(1024) void k_scanb(const int* __restrict__ bcnt,
                                                int* __restrict__ bbase) {
  __shared__ int sc[1024];
  int t = threadIdx.x;
  int v = (t < NBK) ? bcnt[t] : 0;
  sc[t] = v;
  __syncthreads();
  int val = v;
  for (int off = 1; off < 1024; off <<= 1) {
    int x = (t >= off) ? sc[t - off] : 0;
    __syncthreads();
    val += x;
    sc[t] = val;
    __syncthreads();
  }
  if (t < NBK) bbase[t] = val - v;  // exclusive
}

// ---- CSR build: phase 2 FUSED (count pass -> LDS prefix -> ptr write -> scatter) ----
__global__ __launch_bounds__(256) void k_build2(const int* __restrict__ bcnt,
                                                const int* __restrict__ storage,
                                                const int* __restrict__ bbase,
                                                int* __restrict__ ptr,
                                                int* __restrict__ col) {
  __shared__ int c[256];
  __shared__ int sc[256];
  __shared__ int pb[256];
  __shared__ int cur[256];
  int b = blockIdx.x;
  int t = threadIdx.x;
  c[t] = 0;
  __syncthreads();
  int n = bcnt[b];
  const int* s = storage + (size_t)b * CAP;
  for (int i = t; i < n; i += 256) atomicAdd(&c[s[i] >> 17], 1);
  __syncthreads();
  int deg = c[t];
  sc[t] = deg;
  __syncthreads();
  int val = deg;
  for (int off = 1; off < 256; off <<= 1) {
    int x = (t >= off) ? sc[t - off] : 0;
    __syncthreads();
    val += x;
    sc[t] = val;
    __syncthreads();
  }
  int base = bbase[b];
  int myPtr = base + (val - deg);
  pb[t] = myPtr;
  cur[t] = 0;
  int node = b * 256 + t;
  if (node < UI_N) ptr[node] = myPtr;
  if (b == NBK - 1 && t == 255) ptr[UI_N] = base + val;
  __syncthreads();
  for (int i = t; i < n; i += 256) {
    int e = s[i];
    int local = e >> 17;
    int slot = pb[local] + atomicAdd(&cur[local], 1);
    col[slot] = e & 0x1FFFF;
  }
}

// ---------------- Fused active-node flag + compaction (one kernel) ----------------
__global__ void k_flagc(const int* __restrict__ uIdx, const int* __restrict__ iIdx,
                        int* __restrict__ flag, int* __restrict__ list,
                        int* __restrict__ nm) {
  int b = blockIdx.x * blockDim.x + threadIdx.x;
  if (b < B_N) {
    int u = uIdx[b];
    if (atomicExch(&flag[u], 1) == 0) list[atomicAdd(nm, 1)] = u;
    int it = U_N + iIdx[b];
    if (atomicExch(&flag[it], 1) == 0) list[atomicAdd(nm, 1)] = it;
  }
}

// ---------------- Fused matmul + attention scores (users + items, one launch) ---------
__global__ __launch_bounds__(256) void k_mm2(
    const float* __restrict__ Xu32, const float* __restrict__ Xi32,
    const __half* __restrict__ Xu16, const __half* __restrict__ Xi16,
    const float* __restrict__ Wu, const float* __restrict__ Wi,
    const float* __restrict__ a, int layer,
    __half* __restrict__ fA_U, __half* __restrict__ fA_I,
    __half* __restrict__ s16U, __half* __restrict__ s16I) {
  __shared__ float Wl[4096];
  __shared__ float Xs[4096];
  const bool isU = blockIdx.x < NB_U;
  const int N = isU ? U_N : I_N;
  const int base = (isU ? blockIdx.x : blockIdx.x - NB_U) * 64;
  const float* W = isU ? Wu : Wi;
  __half* f16 = isU ? fA_U : fA_I;
  __half* s16 = isU ? s16U : s16I;
  const int aoff = (layer == 1) ? (isU ? 0 : 8) : (isU ? 0 : 64);
  int t = threadIdx.x;

  if (layer == 1) {
#pragma unroll
    for (int k = 0; k < 4; k++) {
      int i = t + 256 * k;
      int h = i >> 7, d = (i >> 1) & 63, half = i & 1;
      float4 v = *(const float4*)(W + h * 512 + d * 8 + half * 4);
      *(float4*)(Wl + d * 64 + h * 8 + half * 4) = v;
    }
    const float* X = isU ? Xu32 : Xi32;
#pragma unroll
    for (int k = 0; k < 4; k++) {
      int i = t + 256 * k;
      int r = i >> 4, ch = i & 15;
      int node = base + r;
      float4 v = make_float4(0.f, 0.f, 0.f, 0.f);
      if (node < N) v = *(const float4*)(X + (size_t)node * 64 + ch * 4);
      *(float4*)(Xs + r * 64 + ch * 4) = v;
    }
  } else {
#pragma unroll
    for (int k = 0; k < 4; k++) {
      int i = t + 256 * k;
      *(float4*)(Wl + i * 4) = *(const float4*)(W + i * 4);
    }
    const __half* X = isU ? Xu16 : Xi16;
#pragma unroll
    for (int k = 0; k < 4; k++) {
      int i = t + 256 * k;
      int r = i >> 4, ch = i & 15;
      int node = base + r;
      float4 v = make_float4(0.f, 0.f, 0.f, 0.f);
      if (node < N) {
        const __half2* hp = (const __half2*)(X + (size_t)node * 64 + ch * 4);
        float2 f0 = __half22float2(hp[0]);
        float2 f1 = __half22float2(hp[1]);
        v = make_float4(f0.x, f0.y, f1.x, f1.y);
      }
      *(float4*)(Xs + r * 64 + ch * 4) = v;
    }
  }
  __syncthreads();

  const int c0 = t & 31;
  const int rb = t >> 5;
  float acc0[8], acc1[8];
#pragma unroll
  for (int k = 0; k < 8; k++) { acc0[k] = 0.f; acc1[k] = 0.f; }

  for (int d0 = 0; d0 < 64; d0 += 4) {
    float2 wA = *(float2*)(Wl + (d0 + 0) * 64 + 2 * c0);
    float2 wB = *(float2*)(Wl + (d0 + 1) * 64 + 2 * c0);
    float2 wC = *(float2*)(Wl + (d0 + 2) * 64 + 2 * c0);
    float2 wD = *(float2*)(Wl + (d0 + 3) * 64 + 2 * c0);
#pragma unroll
    for (int k = 0; k < 8; k++) {
      float4 x = *(float4*)(Xs + (rb + 8 * k) * 64 + d0);
      acc0[k] += x.x * wA.x + x.y * wB.x + x.z * wC.x + x.w * wD.x;
      acc1[k] += x.x * wA.y + x.y * wB.y + x.z * wC.y + x.w * wD.y;
    }
  }

  float av0, av1;
  if (layer == 1) {
    int h = c0 >> 2, j = 2 * (c0 & 3);
    av0 = a[h * 16 + aoff + j];
    av1 = a[h * 16 + aoff + j + 1];
  } else {
    av0 = a[aoff + 2 * c0];
    av1 = a[aoff + 2 * c0 + 1];
  }
#pragma unroll
  for (int k = 0; k < 8; k++) {
    int node = base + rb + 8 * k;
    float s = acc0[k] * av0 + acc1[k] * av1;
    s += __shfl_xor(s, 1);
    s += __shfl_xor(s, 2);
    if (layer != 1) {
      s += __shfl_xor(s, 4);
      s += __shfl_xor(s, 8);
      s += __shfl_xor(s, 16);
    }
    if (node < N) {
      float2 f;
      f.x = acc0[k];
      f.y = acc1[k];
      *(__half2*)(f16 + (size_t)node * 64 + 2 * c0) = __float22half2_rn(f);
      if (layer == 1) {
        if ((c0 & 3) == 0) s16[node * 8 + (c0 >> 2)] = __float2half_rn(s);
      } else {
        if (c0 == 0) s16[node] = __float2half_rn(s);
      }
    }
  }
}

// ---------------- Fused aggregation body: TWO nodes per wave, unroll-4 ----------------
// Inactive half-waves: deg forced to 0 (no loop, no store) — runaway-proof.
template <int LAYER>
__device__ __forceinline__ void agg_body(
    const int* __restrict__ ptr, const int* __restrict__ col,
    const __half* __restrict__ fA_U, const __half* __restrict__ fA_I,
    __half* __restrict__ fB_U, __half* __restrict__ fB_I,
    const __half* __restrict__ s16U, const __half* __restrict__ s16I,
    const int* __restrict__ list, const int* __restrict__ nm) {
  int gid = blockIdx.x * blockDim.x + threadIdx.x;
  int wv = gid >> 6;
  int l = threadIdx.x & 63;
  int half = l >> 5;
  int idx = wv * 2 + half;
  bool act = true;
  int n;
  if (LAYER == 2) {
    act = idx < *nm;
    n = act ? list[idx] : 0;         // node 0 always a valid row
  } else {
    n = idx;                         // UI_N even; pairs never straddle U/I
  }
  int lh = l & 31;
  int g = lh >> 3;
  int cc = lh & 7;
  bool isU = n < U_N;
  int nl = isU ? n : n - U_N;
  const char* nbrF = (const char*)(isU ? fA_I : fA_U);
  const char* nbrS = (const char*)(isU ? s16I : s16U);
  const __half* selfS = isU ? s16U : s16I;
  const __half* selfF = isU ? fA_U : fA_I;
  __half* outp = isU ? fB_U : fB_I;
  const char* colc = (const char*)col;

  int beg = ptr[n], endA = ptr[n + 1];
  int deg = act ? (endA - beg) : 0;  // hazard clamp: inactive -> no loop
  unsigned coff = ((unsigned)(beg + g)) << 2;
  const unsigned begb = (unsigned)beg << 2;
  const unsigned fsh = (unsigned)cc << 4;
  const unsigned ssh = (LAYER == 1) ? ((unsigned)cc << 1) : 0u;
  float sself = (LAYER == 1) ? __half2float(selfS[(size_t)nl * 8 + cc])
                             : __half2float(selfS[nl]);
  float acc[8];
#pragma unroll
  for (int k = 0; k < 8; k++) acc[k] = 0.f;
  float wsum = 0.f;

  auto edge = [&](unsigned off) {
    int nb = *(const int*)(colc + off);
    unsigned so = (LAYER == 1) ? (((unsigned)nb << 4) + ssh) : ((unsigned)nb << 1);
    float x = sself + __half2float(*(const __half*)(nbrS + so));
    float4 r = *(const float4*)(nbrF + (((unsigned)nb << 7) + fsh));
    float w = __expf(-fmaxf(x, 0.2f * x));
    wsum += w;
    const __half* h = (const __half*)&r;
#pragma unroll
    for (int k = 0; k < 8; k++) acc[k] += w * (float)h[k];
  };
  auto edgem = [&](unsigned off, bool valid) {
    unsigned o = valid ? off : begb;
    int nb = *(const int*)(colc + o);
    unsigned so = (LAYER == 1) ? (((unsigned)nb << 4) + ssh) : ((unsigned)nb << 1);
    float x = sself + __half2float(*(const __half*)(nbrS + so));
    float4 r = *(const float4*)(nbrF + (((unsigned)nb << 7) + fsh));
    float w = valid ? __expf(-fmaxf(x, 0.2f * x)) : 0.f;
    wsum += w;
    const __half* h = (const __half*)&r;
#pragma unroll
    for (int k = 0; k < 8; k++) acc[k] += w * (float)h[k];
  };

  int q = deg >> 4;
  for (; q > 0; q--) {
    edge(coff);
    edge(coff + 16);
    edge(coff + 32);
    edge(coff + 48);
    coff += 64;
  }
  int rem = deg & 15;
  if (rem) {
    edgem(coff, g < rem);
    edgem(coff + 16, (4 + g) < rem);
    edgem(coff + 32, (8 + g) < rem);
    edgem(coff + 48, (12 + g) < rem);
  }

#pragma unroll
  for (int k = 0; k < 8; k++) {
    acc[k] += __shfl_xor(acc[k], 8);
    acc[k] += __shfl_xor(acc[k], 16);
  }
  wsum += __shfl_xor(wsum, 8);
  wsum += __shfl_xor(wsum, 16);

  if (lh < 8 && act) {
    float4 raw = *(const float4*)(selfF + (size_t)nl * 64 + cc * 8);
    const __half2* sp = (const __half2*)&raw;
    float2 s0 = __half22float2(sp[0]);
    float2 s1 = __half22float2(sp[1]);
    float2 s2 = __half22float2(sp[2]);
    float2 s3 = __half22float2(sp[3]);
    float v[8] = {s0.x, s0.y, s1.x, s1.y, s2.x, s2.y, s3.x, s3.y};
    if (deg > 0) {
      float inv = 1.f / wsum;
#pragma unroll
      for (int k = 0; k < 8; k++) v[k] += acc[k] * inv;
    }
#pragma unroll
    for (int k = 0; k < 8; k++) v[k] = (v[k] > 0.f) ? v[k] : (__expf(v[k]) - 1.f);
    __half2 o[4];
    o[0] = __floats2half2_rn(v[0], v[1]);
    o[1] = __floats2half2_rn(v[2], v[3]);
    o[2] = __floats2half2_rn(v[4], v[5]);
    o[3] = __floats2half2_rn(v[6], v[7]);
    *(float4*)(outp + (size_t)nl * 64 + cc * 8) = *(float4*)o;
  }
}

__global__ __launch_bounds__(256) void k_aggL1(
    const int* __restrict__ ptr, const int* __restrict__ col,
    const __half* __restrict__ fA_U, const __half* __restrict__ fA_I,
    __half* __restrict__ fB_U, __half* __restrict__ fB_I,
    const __half* __restrict__ s16U, const __half* __restrict__ s16I) {
  agg_body<1>(ptr, col, fA_U, fA_I, fB_U, fB_I, s16U, s16I, nullptr, nullptr);
}

__global__ __launch_bounds__(256) void k_aggL2(
    const int* __restrict__ ptr, const int* __restrict__ col,
    const __half* __restrict__ fA_U, const __half* __restrict__ fA_I,
    __half* __restrict__ fB_U, __half* __restrict__ fB_I,
    const __half* __restrict__ s2U, const __half* __restrict__ s2I,
    const int* __restrict__ list, const int* __restrict__ nm) {
  agg_body<2>(ptr, col, fA_U, fA_I, fB_U, fB_I, s2U, s2I, list, nm);
}

// ---------------- Final pair dot (fp16 inputs; 32 pairs/block, 8 lanes each) ----------
__global__ void k_dot(const int* __restrict__ uIdx, const int* __restrict__ iIdx,
                      const __half* __restrict__ u_f, const __half* __restrict__ i_f,
                      float* __restrict__ out) {
  int t = threadIdx.x;
  int pair = blockIdx.x * 32 + (t >> 3);
  int cc = t & 7;
  float4 ra = *(const float4*)(u_f + (size_t)uIdx[pair] * 64 + cc * 8);
  float4 rb = *(const float4*)(i_f + (size_t)iIdx[pair] * 64 + cc * 8);
  const __half* ha = (const __half*)&ra;
  const __half* hb = (const __half*)&rb;
  float v = 0.f;
#pragma unroll
  for (int k = 0; k < 8; k++) v += (float)ha[k] * (float)hb[k];
  v += __shfl_xor(v, 1);
  v += __shfl_xor(v, 2);
  v += __shfl_xor(v, 4);
  if (cc == 0) out[pair] = v;
}

extern "C" void kernel_launch(void* const* d_in, const int* in_sizes, int n_in,
                              void* d_out, int out_size, void* d_ws, size_t ws_size,
                              hipStream_t stream) {
  const int* userIdx = (const int*)d_in[0];
  const int* itemIdx = (const int*)d_in[1];
  const int* edge_u = (const int*)d_in[2];
  const int* edge_i = (const int*)d_in[3];
  const float* uEmbd = (const float*)d_in[4];
  const float* iEmbd = (const float*)d_in[5];
  const float* Wu_h = (const float*)d_in[6];
  const float* Wi_h = (const float*)d_in[7];
  const float* a_h = (const float*)d_in[8];
  const float* Wu_out = (const float*)d_in[9];
  const float* Wi_out = (const float*)d_in[10];
  const float* a_out = (const float*)d_in[11];
  float* out = (float*)d_out;

  char* w = (char*)d_ws;
  size_t off = 0;
  auto alloc = [&](size_t bytes) -> void* {
    void* p = w + off;
    off += (bytes + 511) & ~(size_t)511;
    return p;
  };
  // zero-init block: bcnt[NBK] | nm[1..pad 16] | flag[UI_N] — one memset
  int* bcnt = (int*)alloc((size_t)(NBK + 16 + UI_N) * 4);
  int* nm = bcnt + NBK;
  int* flag = bcnt + NBK + 16;
  int* ptr = (int*)alloc((size_t)(UI_N + 1) * 4);
  int* bbase = (int*)alloc(4096);
  int* list = (int*)alloc((size_t)MAXACT * 4);
  int* col = (int*)alloc((size_t)COL_CAP * 4);
  // fA (pre-agg gather tables) and scores: NOT aliased with storage
  __half* fA_U = (__half*)alloc((size_t)U_N * 64 * 2);
  __half* fA_I = (__half*)alloc((size_t)I_N * 64 * 2);
  __half* s16U = (__half*)alloc((size_t)U_N * 8 * 2);
  __half* s16I = (__half*)alloc((size_t)I_N * 8 * 2);
  __half* s2U = (__half*)alloc((size_t)U_N * 2);
  __half* s2I = (__half*)alloc((size_t)I_N * 2);
  // union tail: storage (24 MB, dead after k_build2) aliases fB (first write: agg L1)
  size_t union_off = off;
  int* storage = (int*)alloc((size_t)NBK * CAP * 4);
  size_t end_storage = off;
  off = union_off;
  __half* fB_U = (__half*)alloc((size_t)U_N * 64 * 2);
  __half* fB_I = (__half*)alloc((size_t)I_N * 64 * 2);
  if (off < end_storage) off = end_storage;

  // CSR/CSC build (exact rows; count fused into build2) + fused flag/compact
  hipMemsetAsync(bcnt, 0, (size_t)(NBK + 16 + UI_N) * 4, stream);
  k_build1<<<NBLD, 1024, 0, stream>>>(edge_u, edge_i, bcnt, storage);
  k_scanb<<<1, 1024, 0, stream>>>(bcnt, bbase);
  k_build2<<<NBK, 256, 0, stream>>>(bcnt, storage, bbase, ptr, col);
  k_flagc<<<(B_N + 255) / 256, 256, 0, stream>>>(userIdx, itemIdx, flag, list, nm);

  // Layer 1: mm (fp32 in -> fA fp16 + scores); agg over ALL nodes (fA -> fB)
  k_mm2<<<NB_U + NB_I, 256, 0, stream>>>(uEmbd, iEmbd, (const __half*)nullptr,
                                         (const __half*)nullptr, Wu_h, Wi_h, a_h, 1,
                                         fA_U, fA_I, s16U, s16I);
  k_aggL1<<<UI_N * 32 / 256, 256, 0, stream>>>(ptr, col, fA_U, fA_I, fB_U, fB_I,
                                               s16U, s16I);

  // Layer 2: mm over ALL nodes (fB -> fA + s2); agg over ACTIVE nodes only
  k_mm2<<<NB_U + NB_I, 256, 0, stream>>>((const float*)nullptr, (const float*)nullptr,
                                         fB_U, fB_I, Wu_out, Wi_out, a_out, 2,
                                         fA_U, fA_I, s2U, s2I);
  k_aggL2<<<MAXACT * 32 / 256, 256, 0, stream>>>(ptr, col, fA_U, fA_I, fB_U, fB_I,
                                                 s2U, s2I, list, nm);

  // Final per-pair dot (fp16 features)
  k_dot<<<B_N / 32, 256, 0, stream>>>(userIdx, itemIdx, fB_U, fB_I, out);
}